// Round 3
// baseline (98.198 us; speedup 1.0000x reference)
//
#include <hip/hip_runtime.h>
#include <cstdint>

typedef __bf16 v8bf __attribute__((ext_vector_type(8)));
typedef float f32x4 __attribute__((ext_vector_type(4)));
typedef int i32x4 __attribute__((ext_vector_type(4)));
typedef uint16_t u16;
typedef uint32_t u32;
typedef u16 ushort8 __attribute__((ext_vector_type(8)));

__device__ __forceinline__ u16 f2bf(float f) {
  u32 u = __float_as_uint(f);
  u += 0x7FFFu + ((u >> 16) & 1u);   // round-to-nearest-even
  return (u16)(u >> 16);
}
__device__ __forceinline__ float bf2f(u16 h) {
  return __uint_as_float((u32)h << 16);
}

#define AS1(p) ((__attribute__((address_space(1))) void*)(p))
#define AS3(p) ((__attribute__((address_space(3))) void*)(p))

__device__ __forceinline__ v8bf ds_read_b128f(u32 addr) {
  i32x4 r;
  asm volatile("ds_read_b128 %0, %1" : "=v"(r) : "v"(addr));
  return __builtin_bit_cast(v8bf, r);
}

// ---------------- K1: 1/||x_row|| ----------------
__global__ __launch_bounds__(256) void k_rownorm(const float* __restrict__ x,
                                                 float* __restrict__ rnorm) {
  const int row = blockIdx.x;
  const float* p = x + (size_t)row * 1024;
  float s = 0.f;
  for (int c = threadIdx.x; c < 1024; c += 256) { float v = p[c]; s += v * v; }
#pragma unroll
  for (int off = 32; off > 0; off >>= 1) s += __shfl_down(s, off, 64);
  __shared__ float ps[4];
  if ((threadIdx.x & 63) == 0) ps[threadIdx.x >> 6] = s;
  __syncthreads();
  if (threadIdx.x == 0) {
    float t = ps[0] + ps[1] + ps[2] + ps[3];
    rnorm[row] = 1.0f / sqrtf(t);  // norms ~32, eps clamp never binds
  }
}

// ---------------- K2: build Y (bf16, row-major), Yt, Xt (bf16, [1024][8192]) ----------------
__global__ __launch_bounds__(256) void k_build(const float* __restrict__ x,
                                               const float* __restrict__ rnorm,
                                               u16* __restrict__ Y,
                                               u16* __restrict__ Yt,
                                               u16* __restrict__ Xt) {
  __shared__ float tile[64][65];
  __shared__ float rn[64];
  const int d0 = blockIdx.x * 64;   // 0..1023
  const int i0 = blockIdx.y * 64;   // 0..8191
  const int tr = threadIdx.x >> 6;  // 0..3
  const int tc = threadIdx.x & 63;
#pragma unroll
  for (int it = 0; it < 16; ++it) {
    int r = it * 4 + tr;
    tile[r][tc] = x[(size_t)(i0 + r) * 1024 + d0 + tc];
  }
  if (threadIdx.x < 64) rn[threadIdx.x] = rnorm[i0 + threadIdx.x];
  __syncthreads();
#pragma unroll
  for (int it = 0; it < 16; ++it) {
    int r = it * 4 + tr;
    Y[(size_t)(i0 + r) * 1024 + d0 + tc] = f2bf(tile[r][tc] * rn[r]);
  }
#pragma unroll
  for (int it = 0; it < 16; ++it) {
    int rr = it * 4 + tr;            // d within tile
    float v = tile[tc][rr];          // x[i0+tc][d0+rr]
    size_t o = (size_t)(d0 + rr) * 8192 + i0 + tc;
    Xt[o] = f2bf(v);
    Yt[o] = f2bf(v * rn[tc]);
  }
}

// ---------------- GEMM: C = A[M][K] * B[N][K]^T, bf16 in, f32 acc ----------------
// 128x128 tile, 4 waves (2x2), each wave 64x64 = 4x4 frags of 16x16x32 MFMA.
// 3-buffer LDS ring, depth-2 prefetch, counted vmcnt(4). Fragment loads are
// INLINE-ASM ds_read_b128 so the compiler's waitcnt pass cannot insert a
// vmcnt(0) drain before them (it tracks LDS-DMA vs ds_read hazards and would
// otherwise serialize every iteration on the just-issued prefetch).
// EPI==0: bf16 partial store (split-K).  EPI==1: sigmoid(acc + x*rn*zdiag) f32.
template <int EPI>
__global__ __launch_bounds__(256, 3) void k_gemm_bt(
    const u16* __restrict__ A, const u16* __restrict__ B, void* __restrict__ Cv,
    int N, int K, int k_len, size_t c_split_stride,
    const float* __restrict__ Xf, const float* __restrict__ rnorm,
    const float* __restrict__ zdiag) {
  // per buffer: A tile [128][32] u16 (8KB) at +0, B tile at +8192
  __shared__ char lds[3][16384] __attribute__((aligned(16)));
  const int tid = threadIdx.x;
  const int wave = tid >> 6;
  const int lane = tid & 63;
  const int wm = wave >> 1, wn = wave & 1;
  const int m0 = blockIdx.y * 128;
  const int n0 = blockIdx.x * 128;
  const int k_start = blockIdx.z * k_len;

  f32x4 acc[4][4] = {};

  const int frow = lane & 15;
  const int fkb = (lane >> 4) * 16;          // byte offset of 8-elem k-chunk

  // staging geometry: per operand 8KB/tile; wave w covers [w*2048, w*2048+2048)
  // as two 1KB issues; lane l writes LDS base + l*16 (HW: uniform base + lane*16)
  const int o0 = wave * 2048 + lane * 16;
  const int s_row0 = o0 >> 6;                // tile row of this lane, issue 0
  const int s_ce = (o0 & 63) >> 1;           // k-element within row
  const int s_row1 = (o0 + 1024) >> 6;

  const u16* gA0 = A + (size_t)(m0 + s_row0) * K + k_start + s_ce;
  const u16* gA1 = A + (size_t)(m0 + s_row1) * K + k_start + s_ce;
  const u16* gB0 = B + (size_t)(n0 + s_row0) * K + k_start + s_ce;
  const u16* gB1 = B + (size_t)(n0 + s_row1) * K + k_start + s_ce;

  typedef __attribute__((address_space(3))) char* ldsp;
  ldsp l3 = (ldsp)AS3(&lds[0][0]);
  const u32 lds0 = (u32)(uintptr_t)l3;

#define STAGE(buf, kt)                                                                     \
  do {                                                                                     \
    const int _kk = (kt) * 32;                                                             \
    ldsp _b = l3 + (buf) * 16384 + wave * 2048;                                            \
    __builtin_amdgcn_global_load_lds(AS1(gA0 + _kk), (_b), 16, 0, 0);                      \
    __builtin_amdgcn_global_load_lds(AS1(gA1 + _kk), (_b + 1024), 16, 0, 0);               \
    __builtin_amdgcn_global_load_lds(AS1(gB0 + _kk), (_b + 8192), 16, 0, 0);               \
    __builtin_amdgcn_global_load_lds(AS1(gB1 + _kk), (_b + 9216), 16, 0, 0);               \
  } while (0)

#define COMPUTE(buf)                                                                       \
  do {                                                                                     \
    v8bf af[4], bfr[4];                                                                    \
    const u32 baseA = lds0 + (u32)(buf) * 16384 + (wm * 64 + frow) * 64 + fkb;             \
    const u32 baseB = lds0 + (u32)(buf) * 16384 + 8192 + (wn * 64 + frow) * 64 + fkb;      \
    _Pragma("unroll")                                                                      \
    for (int i = 0; i < 4; ++i) {                                                          \
      af[i] = ds_read_b128f(baseA + i * 1024);                                             \
      bfr[i] = ds_read_b128f(baseB + i * 1024);                                            \
    }                                                                                      \
    asm volatile("s_waitcnt lgkmcnt(0)" ::: "memory");                                     \
    __builtin_amdgcn_sched_barrier(0);                                                     \
    __builtin_amdgcn_s_setprio(1);                                                         \
    _Pragma("unroll")                                                                      \
    for (int mi = 0; mi < 4; ++mi)                                                         \
      _Pragma("unroll")                                                                    \
      for (int ni = 0; ni < 4; ++ni)                                                       \
        acc[mi][ni] = __builtin_amdgcn_mfma_f32_16x16x32_bf16(af[mi], bfr[ni], acc[mi][ni], 0, 0, 0); \
    __builtin_amdgcn_s_setprio(0);                                                         \
  } while (0)

  const int nt = k_len >> 5;  // 16 (GEMM1) / 32 (GEMM2)
  STAGE(0, 0);
  STAGE(1, 1);
  int cur = 0;
  for (int t = 0; t < nt - 1; ++t) {
    asm volatile("s_waitcnt vmcnt(4)" ::: "memory");  // tile t staged; t+1 still in flight
    __builtin_amdgcn_s_barrier();
    const int nxt2 = (cur + 2 >= 3) ? cur - 1 : cur + 2;
    if (t + 2 < nt) STAGE(nxt2, t + 2);
    COMPUTE(cur);
    cur = (cur + 1 >= 3) ? cur - 2 : cur + 1;
  }
  asm volatile("s_waitcnt vmcnt(0)" ::: "memory");
  __builtin_amdgcn_s_barrier();
  COMPUTE(cur);
#undef STAGE
#undef COMPUTE

  // C/D layout (verified): col = lane&15, row = (lane>>4)*4 + reg
  const int crow = (lane >> 4) * 4;
  const int ccol = lane & 15;
#pragma unroll
  for (int mi = 0; mi < 4; ++mi) {
#pragma unroll
    for (int ni = 0; ni < 4; ++ni) {
      const int row = m0 + wm * 64 + mi * 16 + crow;
      const int col = n0 + wn * 64 + ni * 16 + ccol;
#pragma unroll
      for (int r = 0; r < 4; ++r) {
        const size_t o = (size_t)(row + r) * N + col;
        float v = acc[mi][ni][r];
        if (EPI == 0) {
          ((u16*)Cv)[(size_t)blockIdx.z * c_split_stride + o] = f2bf(v);  // bf16 partial
        } else {
          float z = v + Xf[o] * rnorm[row + r] * zdiag[col];  // exact diag term
          ((float*)Cv)[o] = 1.0f / (1.0f + __expf(-z));
        }
      }
    }
  }
}

// ---------------- K4: reduce 16 bf16 split-K partials -> bf16 Z (diag zeroed, saved f32) ----------------
__global__ __launch_bounds__(256) void k_reduce1(const u16* __restrict__ part,
                                                 u16* __restrict__ Ztb,
                                                 float* __restrict__ zdiag) {
  const int v = blockIdx.x * 256 + threadIdx.x;  // 0..131071
  const int base = v * 8;                        // over 1024*1024, 8 at a time
  float s[8] = {0, 0, 0, 0, 0, 0, 0, 0};
#pragma unroll
  for (int p = 0; p < 16; ++p) {
    ushort8 pk = *(const ushort8*)(part + ((size_t)p << 20) + base);
#pragma unroll
    for (int j = 0; j < 8; ++j) s[j] += bf2f(pk[j]);
  }
  const int m = base >> 10, n0c = base & 1023;
  ushort8 o;
#pragma unroll
  for (int j = 0; j < 8; ++j) {
    if (m == n0c + j) { zdiag[m] = s[j]; o[j] = 0; }
    else o[j] = f2bf(s[j]);
  }
  *(ushort8*)(Ztb + base) = o;
}

extern "C" void kernel_launch(void* const* d_in, const int* in_sizes, int n_in,
                              void* d_out, int out_size, void* d_ws, size_t ws_size,
                              hipStream_t stream) {
  const float* x = (const float*)d_in[0];
  float* out = (float*)d_out;
  char* ws = (char*)d_ws;

  // ws layout (~50.1 MB): rnorm | Y | Yt | Xt | Ztb | zdiag
  float* rnorm = (float*)ws;                                   // 32 KB
  u16* Y    = (u16*)(ws + (1u << 16));                         // 16 MB
  u16* Yt   = (u16*)(ws + (1u << 16) + (16u << 20));           // 16 MB
  u16* Xt   = (u16*)(ws + (1u << 16) + (32u << 20));           // 16 MB
  u16* Ztb  = (u16*)(ws + (1u << 16) + (48u << 20));           // 2 MB
  float* zdiag = (float*)(ws + (1u << 16) + (50u << 20));      // 4 KB
  u16* part = (u16*)d_out;  // 16 x 2 MB bf16 split-K partials, consumed by k_reduce1

  k_rownorm<<<8192, 256, 0, stream>>>(x, rnorm);
  k_build<<<dim3(16, 128), 256, 0, stream>>>(x, rnorm, Y, Yt, Xt);
  // Zt[d][k] = sum_i Xt[d][i] * Yt[k][i], K=8192, split-K=16 -> 1024 blocks
  k_gemm_bt<0><<<dim3(8, 8, 16), 256, 0, stream>>>(Xt, Yt, part, 1024, 8192, 512,
                                                   (size_t)1 << 20, nullptr, nullptr, nullptr);
  k_reduce1<<<512, 256, 0, stream>>>(part, Ztb, zdiag);
  // out[i][d] = sigmoid( sum_k Y[i][k]*Zt[d][k] + x[i][d]*rn[i]*zdiag[d] )
  k_gemm_bt<1><<<dim3(8, 64, 1), 256, 0, stream>>>(Y, Ztb, out, 1024, 1024, 1024,
                                                   0, x, rnorm, zdiag);
}

// Round 4
// 91.907 us; speedup vs baseline: 1.0685x; 1.0685x over previous
//
#include <hip/hip_runtime.h>
#include <cstdint>

typedef __bf16 v8bf __attribute__((ext_vector_type(8)));
typedef float f32x4 __attribute__((ext_vector_type(4)));
typedef int i32x4 __attribute__((ext_vector_type(4)));
typedef uint16_t u16;
typedef uint32_t u32;
typedef u16 ushort8 __attribute__((ext_vector_type(8)));

__device__ __forceinline__ u16 f2bf(float f) {
  u32 u = __float_as_uint(f);
  u += 0x7FFFu + ((u >> 16) & 1u);   // round-to-nearest-even
  return (u16)(u >> 16);
}
__device__ __forceinline__ float bf2f(u16 h) {
  return __uint_as_float((u32)h << 16);
}

#define AS1(p) ((__attribute__((address_space(1))) void*)(p))

__device__ __forceinline__ v8bf ds_read_b128f(u32 addr) {
  i32x4 r;
  asm volatile("ds_read_b128 %0, %1" : "=v"(r) : "v"(addr));
  return __builtin_bit_cast(v8bf, r);
}

// ---------------- K1: 1/||x_row|| ----------------
__global__ __launch_bounds__(256) void k_rownorm(const float* __restrict__ x,
                                                 float* __restrict__ rnorm) {
  const int row = blockIdx.x;
  const float* p = x + (size_t)row * 1024;
  float s = 0.f;
  for (int c = threadIdx.x; c < 1024; c += 256) { float v = p[c]; s += v * v; }
#pragma unroll
  for (int off = 32; off > 0; off >>= 1) s += __shfl_down(s, off, 64);
  __shared__ float ps[4];
  if ((threadIdx.x & 63) == 0) ps[threadIdx.x >> 6] = s;
  __syncthreads();
  if (threadIdx.x == 0) {
    float t = ps[0] + ps[1] + ps[2] + ps[3];
    rnorm[row] = 1.0f / sqrtf(t);  // norms ~32, eps clamp never binds
  }
}

// ---------------- K2: build Y (bf16, row-major), Yt, Xt (bf16, [1024][8192]) ----------------
__global__ __launch_bounds__(256) void k_build(const float* __restrict__ x,
                                               const float* __restrict__ rnorm,
                                               u16* __restrict__ Y,
                                               u16* __restrict__ Yt,
                                               u16* __restrict__ Xt) {
  __shared__ float tile[64][65];
  __shared__ float rn[64];
  const int d0 = blockIdx.x * 64;   // 0..1023
  const int i0 = blockIdx.y * 64;   // 0..8191
  const int tr = threadIdx.x >> 6;  // 0..3
  const int tc = threadIdx.x & 63;
#pragma unroll
  for (int it = 0; it < 16; ++it) {
    int r = it * 4 + tr;
    tile[r][tc] = x[(size_t)(i0 + r) * 1024 + d0 + tc];
  }
  if (threadIdx.x < 64) rn[threadIdx.x] = rnorm[i0 + threadIdx.x];
  __syncthreads();
#pragma unroll
  for (int it = 0; it < 16; ++it) {
    int r = it * 4 + tr;
    Y[(size_t)(i0 + r) * 1024 + d0 + tc] = f2bf(tile[r][tc] * rn[r]);
  }
#pragma unroll
  for (int it = 0; it < 16; ++it) {
    int rr = it * 4 + tr;            // d within tile
    float v = tile[tc][rr];          // x[i0+tc][d0+rr]
    size_t o = (size_t)(d0 + rr) * 8192 + i0 + tc;
    Xt[o] = f2bf(v);
    Yt[o] = f2bf(v * rn[tc]);
  }
}

// ---------------- GEMM: C = A[M][K] * B[N][K]^T, bf16 in, f32 acc ----------------
// 128x128 tile, BK=64, 4 waves (2x2), each wave 64x64 = 4x4 frags, 32 MFMA/tile.
// LDS tile per operand: [128 rows][128B], XOR-swizzled: 16B-slot ^= (row&7).
// global_load_lds writes linearly, so the per-lane GLOBAL source address is
// pre-swizzled (slot' = (lane&7)^((lane>>3)&7) — a permutation of each 128B
// row, coalescing preserved) and the ds_read applies the same XOR (rule #21).
// 2-buffer ring, depth-1 prefetch, counted vmcnt(8) (8 loads/wave/tile).
// EPI==0: bf16 partial store (split-K).  EPI==1: sigmoid(acc + x*rn*zdiag) f32.
template <int EPI>
__global__ __launch_bounds__(256, 2) void k_gemm_bt(
    const u16* __restrict__ A, const u16* __restrict__ B, void* __restrict__ Cv,
    int N, int K, int k_len, size_t c_split_stride,
    const float* __restrict__ Xf, const float* __restrict__ rnorm,
    const float* __restrict__ zdiag) {
  // per buffer (32KB): A tile [128][128B] at +0, B tile at +16384; 2 buffers
  __shared__ char lds[2][32768] __attribute__((aligned(16)));
  const int tid = threadIdx.x;
  const int wave = tid >> 6;
  const int lane = tid & 63;
  const int wm = wave >> 1, wn = wave & 1;
  const int m0 = blockIdx.y * 128;
  const int n0 = blockIdx.x * 128;
  const int k_start = blockIdx.z * k_len;

  f32x4 acc[4][4] = {};

  const int frow = lane & 15;
  const int fslot = lane >> 4;               // 0..3 (16B k-slot within 64B half)
  const u32 sw0 = (u32)((fslot ^ (frow & 7)) << 4);  // swizzled slot, k-step 0
  // k-step 1 slot = (fslot+4)^(frow&7) = sw0 ^ 0x40

  // staging: wave covers rows [wave*32, wave*32+32) of each operand tile as
  // 4 x 1KB issues (8 rows each). lane l -> row wave*32+j*8+(l>>3), global
  // k-slot (l&7)^((l>>3)&7) (inverse swizzle), LDS dest linear base+l*16.
  const int srow = wave * 32 + (lane >> 3);
  const int swz8 = (((lane & 7) ^ ((lane >> 3) & 7)) << 3);  // element offset
  const u16* gA_l = A + (size_t)(m0 + srow) * K + k_start + swz8;
  const u16* gB_l = B + (size_t)(n0 + srow) * K + k_start + swz8;

  typedef __attribute__((address_space(3))) char* ldsp;
  ldsp l3 = (ldsp)((__attribute__((address_space(3))) void*)&lds[0][0]);
  const u32 lds0 = (u32)(uintptr_t)l3;

#define STAGE(buf, kt)                                                         \
  do {                                                                         \
    const size_t _ko = (size_t)(kt) * 64;                                      \
    ldsp _ba = l3 + (buf) * 32768 + wave * 4096;                               \
    _Pragma("unroll")                                                          \
    for (int _j = 0; _j < 4; ++_j) {                                           \
      __builtin_amdgcn_global_load_lds(AS1(gA_l + _ko + (size_t)_j * 8 * K),   \
                                       (_ba + _j * 1024), 16, 0, 0);           \
      __builtin_amdgcn_global_load_lds(AS1(gB_l + _ko + (size_t)_j * 8 * K),   \
                                       (_ba + 16384 + _j * 1024), 16, 0, 0);   \
    }                                                                          \
  } while (0)

#define COMPUTE(buf)                                                                       \
  do {                                                                                     \
    const u32 bb = lds0 + (u32)(buf) * 32768;                                              \
    const u32 aA = bb + (u32)((wm * 64 + frow) * 128) + sw0;                               \
    const u32 aB = bb + 16384 + (u32)((wn * 64 + frow) * 128) + sw0;                       \
    v8bf a0[4], b0[4], a1[4], b1[4];                                                       \
    _Pragma("unroll")                                                                      \
    for (int i = 0; i < 4; ++i) a0[i] = ds_read_b128f(aA + i * 2048);                      \
    _Pragma("unroll")                                                                      \
    for (int i = 0; i < 4; ++i) b0[i] = ds_read_b128f(aB + i * 2048);                      \
    _Pragma("unroll")                                                                      \
    for (int i = 0; i < 4; ++i) a1[i] = ds_read_b128f((aA + i * 2048) ^ 0x40);             \
    _Pragma("unroll")                                                                      \
    for (int i = 0; i < 4; ++i) b1[i] = ds_read_b128f((aB + i * 2048) ^ 0x40);             \
    asm volatile("s_waitcnt lgkmcnt(8)" ::: "memory");                                     \
    __builtin_amdgcn_sched_barrier(0);                                                     \
    __builtin_amdgcn_s_setprio(1);                                                         \
    _Pragma("unroll")                                                                      \
    for (int mi = 0; mi < 4; ++mi)                                                         \
      _Pragma("unroll")                                                                    \
      for (int ni = 0; ni < 4; ++ni)                                                       \
        acc[mi][ni] = __builtin_amdgcn_mfma_f32_16x16x32_bf16(a0[mi], b0[ni], acc[mi][ni], 0, 0, 0); \
    asm volatile("s_waitcnt lgkmcnt(0)" ::: "memory");                                     \
    __builtin_amdgcn_sched_barrier(0);                                                     \
    _Pragma("unroll")                                                                      \
    for (int mi = 0; mi < 4; ++mi)                                                         \
      _Pragma("unroll")                                                                    \
      for (int ni = 0; ni < 4; ++ni)                                                       \
        acc[mi][ni] = __builtin_amdgcn_mfma_f32_16x16x32_bf16(a1[mi], b1[ni], acc[mi][ni], 0, 0, 0); \
    __builtin_amdgcn_s_setprio(0);                                                         \
  } while (0)

  const int nt = k_len >> 6;  // 16 for both GEMMs (BK=64)
  STAGE(0, 0);
  STAGE(1, 1);
  for (int t = 0; t < nt; ++t) {
    if (t < nt - 1) {
      asm volatile("s_waitcnt vmcnt(8)" ::: "memory");   // tile t staged; t+1 in flight
    } else {
      asm volatile("s_waitcnt vmcnt(0)" ::: "memory");
    }
    __builtin_amdgcn_s_barrier();
    COMPUTE(t & 1);
    __builtin_amdgcn_s_barrier();                        // all waves done reading buf t&1
    if (t + 2 < nt) STAGE(t & 1, t + 2);
  }
#undef STAGE
#undef COMPUTE

  // C/D layout (verified): col = lane&15, row = (lane>>4)*4 + reg
  const int crow = (lane >> 4) * 4;
  const int ccol = lane & 15;
#pragma unroll
  for (int mi = 0; mi < 4; ++mi) {
#pragma unroll
    for (int ni = 0; ni < 4; ++ni) {
      const int row = m0 + wm * 64 + mi * 16 + crow;
      const int col = n0 + wn * 64 + ni * 16 + ccol;
#pragma unroll
      for (int r = 0; r < 4; ++r) {
        const size_t o = (size_t)(row + r) * N + col;
        float v = acc[mi][ni][r];
        if (EPI == 0) {
          ((u16*)Cv)[(size_t)blockIdx.z * c_split_stride + o] = f2bf(v);  // bf16 partial
        } else {
          float z = v + Xf[o] * rnorm[row + r] * zdiag[col];  // exact diag term
          ((float*)Cv)[o] = 1.0f / (1.0f + __expf(-z));
        }
      }
    }
  }
}

// ---------------- K4: reduce 8 bf16 split-K partials -> bf16 Z (diag zeroed, saved f32) ----------------
__global__ __launch_bounds__(256) void k_reduce1(const u16* __restrict__ part,
                                                 u16* __restrict__ Ztb,
                                                 float* __restrict__ zdiag) {
  const int v = blockIdx.x * 256 + threadIdx.x;  // 0..131071
  const int base = v * 8;                        // over 1024*1024, 8 at a time
  float s[8] = {0, 0, 0, 0, 0, 0, 0, 0};
#pragma unroll
  for (int p = 0; p < 8; ++p) {
    ushort8 pk = *(const ushort8*)(part + ((size_t)p << 20) + base);
#pragma unroll
    for (int j = 0; j < 8; ++j) s[j] += bf2f(pk[j]);
  }
  const int m = base >> 10, n0c = base & 1023;
  ushort8 o;
#pragma unroll
  for (int j = 0; j < 8; ++j) {
    if (m == n0c + j) { zdiag[m] = s[j]; o[j] = 0; }
    else o[j] = f2bf(s[j]);
  }
  *(ushort8*)(Ztb + base) = o;
}

extern "C" void kernel_launch(void* const* d_in, const int* in_sizes, int n_in,
                              void* d_out, int out_size, void* d_ws, size_t ws_size,
                              hipStream_t stream) {
  const float* x = (const float*)d_in[0];
  float* out = (float*)d_out;
  char* ws = (char*)d_ws;

  // ws layout (~50.1 MB): rnorm | Y | Yt | Xt | Ztb | zdiag
  float* rnorm = (float*)ws;                                   // 32 KB
  u16* Y    = (u16*)(ws + (1u << 16));                         // 16 MB
  u16* Yt   = (u16*)(ws + (1u << 16) + (16u << 20));           // 16 MB
  u16* Xt   = (u16*)(ws + (1u << 16) + (32u << 20));           // 16 MB
  u16* Ztb  = (u16*)(ws + (1u << 16) + (48u << 20));           // 2 MB
  float* zdiag = (float*)(ws + (1u << 16) + (50u << 20));      // 4 KB
  u16* part = (u16*)d_out;  // 8 x 2 MB bf16 split-K partials, consumed by k_reduce1

  k_rownorm<<<8192, 256, 0, stream>>>(x, rnorm);
  k_build<<<dim3(16, 128), 256, 0, stream>>>(x, rnorm, Y, Yt, Xt);
  // Zt[d][k] = sum_i Xt[d][i] * Yt[k][i], K=8192, split-K=8 -> 512 blocks
  k_gemm_bt<0><<<dim3(8, 8, 8), 256, 0, stream>>>(Xt, Yt, part, 1024, 8192, 1024,
                                                  (size_t)1 << 20, nullptr, nullptr, nullptr);
  k_reduce1<<<512, 256, 0, stream>>>(part, Ztb, zdiag);
  // out[i][d] = sigmoid( sum_k Y[i][k]*Zt[d][k] + x[i][d]*rn[i]*zdiag[d] )
  k_gemm_bt<1><<<dim3(8, 64, 1), 256, 0, stream>>>(Y, Ztb, out, 1024, 1024, 1024,
                                                   0, x, rnorm, zdiag);
}

// Round 5
// 79.781 us; speedup vs baseline: 1.2308x; 1.1520x over previous
//
#include <hip/hip_runtime.h>
#include <cstdint>

typedef __bf16 v8bf __attribute__((ext_vector_type(8)));
typedef float f32x4 __attribute__((ext_vector_type(4)));
typedef int i32x4 __attribute__((ext_vector_type(4)));
typedef uint16_t u16;
typedef uint32_t u32;
typedef u16 ushort8 __attribute__((ext_vector_type(8)));

__device__ __forceinline__ u16 f2bf(float f) {
  u32 u = __float_as_uint(f);
  u += 0x7FFFu + ((u >> 16) & 1u);   // round-to-nearest-even
  return (u16)(u >> 16);
}
__device__ __forceinline__ float bf2f(u16 h) {
  return __uint_as_float((u32)h << 16);
}

#define AS1(p) ((__attribute__((address_space(1))) void*)(p))

__device__ __forceinline__ v8bf ds_read_b128f(u32 addr) {
  i32x4 r;
  asm volatile("ds_read_b128 %0, %1" : "=v"(r) : "v"(addr));
  return __builtin_bit_cast(v8bf, r);
}

// Counted waits: NO clobbers (a "memory" clobber makes SIInsertWaitcnts treat
// the asm as a memory access and insert vmcnt(0) lgkmcnt(0) before it,
// serializing the pipeline). Ordering is pinned with sched_barrier(0).
#define WAITV(N)                                         \
  do {                                                   \
    __builtin_amdgcn_sched_barrier(0);                   \
    asm volatile("s_waitcnt vmcnt(" #N ")");             \
    __builtin_amdgcn_sched_barrier(0);                   \
  } while (0)
#define WAITL(N)                                         \
  do {                                                   \
    __builtin_amdgcn_sched_barrier(0);                   \
    asm volatile("s_waitcnt lgkmcnt(" #N ")");           \
    __builtin_amdgcn_sched_barrier(0);                   \
  } while (0)

// ---------------- K1: 1/||x_row|| ----------------
__global__ __launch_bounds__(256) void k_rownorm(const float* __restrict__ x,
                                                 float* __restrict__ rnorm) {
  const int row = blockIdx.x;
  const float* p = x + (size_t)row * 1024;
  float s = 0.f;
  for (int c = threadIdx.x; c < 1024; c += 256) { float v = p[c]; s += v * v; }
#pragma unroll
  for (int off = 32; off > 0; off >>= 1) s += __shfl_down(s, off, 64);
  __shared__ float ps[4];
  if ((threadIdx.x & 63) == 0) ps[threadIdx.x >> 6] = s;
  __syncthreads();
  if (threadIdx.x == 0) {
    float t = ps[0] + ps[1] + ps[2] + ps[3];
    rnorm[row] = 1.0f / sqrtf(t);  // norms ~32, eps clamp never binds
  }
}

// ---------------- K2: build Y (bf16, row-major), Yt, Xt (bf16, [1024][8192]) ----------------
__global__ __launch_bounds__(256) void k_build(const float* __restrict__ x,
                                               const float* __restrict__ rnorm,
                                               u16* __restrict__ Y,
                                               u16* __restrict__ Yt,
                                               u16* __restrict__ Xt) {
  __shared__ float tile[64][65];
  __shared__ float rn[64];
  const int d0 = blockIdx.x * 64;   // 0..1023
  const int i0 = blockIdx.y * 64;   // 0..8191
  const int tr = threadIdx.x >> 6;  // 0..3
  const int tc = threadIdx.x & 63;
#pragma unroll
  for (int it = 0; it < 16; ++it) {
    int r = it * 4 + tr;
    tile[r][tc] = x[(size_t)(i0 + r) * 1024 + d0 + tc];
  }
  if (threadIdx.x < 64) rn[threadIdx.x] = rnorm[i0 + threadIdx.x];
  __syncthreads();
#pragma unroll
  for (int it = 0; it < 16; ++it) {
    int r = it * 4 + tr;
    Y[(size_t)(i0 + r) * 1024 + d0 + tc] = f2bf(tile[r][tc] * rn[r]);
  }
#pragma unroll
  for (int it = 0; it < 16; ++it) {
    int rr = it * 4 + tr;            // d within tile
    float v = tile[tc][rr];          // x[i0+tc][d0+rr]
    size_t o = (size_t)(d0 + rr) * 8192 + i0 + tc;
    Xt[o] = f2bf(v);
    Yt[o] = f2bf(v * rn[tc]);
  }
}

// ---------------- GEMM: C = A[M][K] * B[N][K]^T, bf16 in, f32 acc ----------------
// 128x128 tile, BK=64, 4 waves (2x2), XOR-swizzled LDS (conflict-free, R4-verified),
// 2-buffer ring, depth-1 prefetch, counted vmcnt(8) with clobber-free waits.
// MODE 0 (GEMM1): Z = Xt*Yt^T lower-triangle tiles only (Z symmetric), split-K=16,
//   blockIdx.x bijectively decoded (XCD-chunked by z-slice), bf16 partial out.
// MODE 1 (GEMM2): out = sigmoid(Y*Ztb^T + x*rn*zdiag), XCD-chunked by m-panel.
template <int MODE>
__global__ __launch_bounds__(256, 2) void k_gemm_bt(
    const u16* __restrict__ A, const u16* __restrict__ B, void* __restrict__ Cv,
    const float* __restrict__ Xf, const float* __restrict__ rnorm,
    const float* __restrict__ zdiag) {
  __shared__ char lds[2][32768] __attribute__((aligned(16)));
  const int tid = threadIdx.x;
  const int wave = tid >> 6;
  const int lane = tid & 63;
  const int wm = wave >> 1, wn = wave & 1;

  int m0, n0, k_start, K, nt;
  int tl = 0, zi = 0;
  if (MODE == 0) {
    // 576 blocks: xcd = orig&7 gets z-slices {2*xcd, 2*xcd+1} (4MB L2 set)
    const int orig = blockIdx.x;
    const int xcd = orig & 7;
    const int local = orig >> 3;            // 0..71
    const int half = (local >= 36) ? 1 : 0;
    tl = local - half * 36;                 // 0..35 lower-tri tile id
    zi = xcd * 2 + half;                    // 0..15 split-K slice
    int tm = 0, a2 = 0;
    while (a2 + tm + 1 <= tl) { ++tm; a2 += tm; }
    const int tn = tl - a2;                 // tn <= tm
    m0 = tm * 128; n0 = tn * 128;
    k_start = zi * 512; K = 8192; nt = 8;   // k_len=512, BK=64
  } else {
    // 512 blocks: xcd = orig&7 gets 8 m-panels (2MB Y + 2MB Ztb in L2)
    const int orig = blockIdx.x;
    const int xcd = orig & 7;
    const int local = orig >> 3;            // 0..63
    const int mt = xcd * 8 + (local >> 3);  // 0..63
    const int ntc = local & 7;              // 0..7
    m0 = mt * 128; n0 = ntc * 128;
    k_start = 0; K = 1024; nt = 16;
  }

  f32x4 acc[4][4] = {};

  const int frow = lane & 15;
  const int fslot = lane >> 4;               // 16B k-slot
  const u32 sw0 = (u32)((fslot ^ (frow & 7)) << 4);

  const int srow = wave * 32 + (lane >> 3);
  const int swz8 = (((lane & 7) ^ ((lane >> 3) & 7)) << 3);
  const u16* gA_l = A + (size_t)(m0 + srow) * K + k_start + swz8;
  const u16* gB_l = B + (size_t)(n0 + srow) * K + k_start + swz8;

  typedef __attribute__((address_space(3))) char* ldsp;
  ldsp l3 = (ldsp)((__attribute__((address_space(3))) void*)&lds[0][0]);
  const u32 lds0 = (u32)(uintptr_t)l3;

#define STAGE(buf, kt)                                                         \
  do {                                                                         \
    const size_t _ko = (size_t)(kt) * 64;                                      \
    ldsp _ba = l3 + (buf) * 32768 + wave * 4096;                               \
    _Pragma("unroll")                                                          \
    for (int _j = 0; _j < 4; ++_j) {                                           \
      __builtin_amdgcn_global_load_lds(AS1(gA_l + _ko + (size_t)_j * 8 * K),   \
                                       (_ba + _j * 1024), 16, 0, 0);           \
      __builtin_amdgcn_global_load_lds(AS1(gB_l + _ko + (size_t)_j * 8 * K),   \
                                       (_ba + 16384 + _j * 1024), 16, 0, 0);   \
    }                                                                          \
  } while (0)

#define COMPUTE(buf)                                                                       \
  do {                                                                                     \
    const u32 bb = lds0 + (u32)(buf) * 32768;                                              \
    const u32 aA = bb + (u32)((wm * 64 + frow) * 128) + sw0;                               \
    const u32 aB = bb + 16384 + (u32)((wn * 64 + frow) * 128) + sw0;                       \
    v8bf a0[4], b0[4], a1[4], b1[4];                                                       \
    _Pragma("unroll")                                                                      \
    for (int i = 0; i < 4; ++i) a0[i] = ds_read_b128f(aA + i * 2048);                      \
    _Pragma("unroll")                                                                      \
    for (int i = 0; i < 4; ++i) b0[i] = ds_read_b128f(aB + i * 2048);                      \
    _Pragma("unroll")                                                                      \
    for (int i = 0; i < 4; ++i) a1[i] = ds_read_b128f((aA + i * 2048) ^ 0x40);             \
    _Pragma("unroll")                                                                      \
    for (int i = 0; i < 4; ++i) b1[i] = ds_read_b128f((aB + i * 2048) ^ 0x40);             \
    WAITL(8);                                                                              \
    __builtin_amdgcn_s_setprio(1);                                                         \
    _Pragma("unroll")                                                                      \
    for (int mi = 0; mi < 4; ++mi)                                                         \
      _Pragma("unroll")                                                                    \
      for (int ni = 0; ni < 4; ++ni)                                                       \
        acc[mi][ni] = __builtin_amdgcn_mfma_f32_16x16x32_bf16(a0[mi], b0[ni], acc[mi][ni], 0, 0, 0); \
    WAITL(0);                                                                              \
    _Pragma("unroll")                                                                      \
    for (int mi = 0; mi < 4; ++mi)                                                         \
      _Pragma("unroll")                                                                    \
      for (int ni = 0; ni < 4; ++ni)                                                       \
        acc[mi][ni] = __builtin_amdgcn_mfma_f32_16x16x32_bf16(a1[mi], b1[ni], acc[mi][ni], 0, 0, 0); \
    __builtin_amdgcn_s_setprio(0);                                                         \
  } while (0)

  STAGE(0, 0);
  STAGE(1, 1);
  for (int t = 0; t < nt; ++t) {
    if (t < nt - 1) {
      WAITV(8);            // tile t staged; t+1 still in flight
    } else {
      WAITV(0);
    }
    __builtin_amdgcn_s_barrier();
    COMPUTE(t & 1);
    __builtin_amdgcn_s_barrier();          // all waves done reading buf t&1
    if (t + 2 < nt) STAGE(t & 1, t + 2);
  }
#undef STAGE
#undef COMPUTE

  // C/D layout (verified): col = lane&15, row = (lane>>4)*4 + reg
  const int crow = (lane >> 4) * 4;
  const int ccol = lane & 15;
#pragma unroll
  for (int mi = 0; mi < 4; ++mi) {
#pragma unroll
    for (int ni = 0; ni < 4; ++ni) {
      const int rl = wm * 64 + mi * 16 + crow;
      const int cl = wn * 64 + ni * 16 + ccol;
#pragma unroll
      for (int r = 0; r < 4; ++r) {
        float v = acc[mi][ni][r];
        if (MODE == 0) {
          // partial tile store: part[zi][tl][rl+r][cl] bf16
          const size_t o = ((size_t)zi * 36 + tl) * 16384 + (size_t)(rl + r) * 128 + cl;
          ((u16*)Cv)[o] = f2bf(v);
        } else {
          const int row = m0 + rl + r;
          const int col = n0 + cl;
          const size_t o = (size_t)row * 1024 + col;
          float z = v + Xf[o] * rnorm[row] * zdiag[col];  // exact diag term
          ((float*)Cv)[o] = 1.0f / (1.0f + __expf(-z));
        }
      }
    }
  }
}

// ---------------- K4: reduce 16 bf16 partials over lower-tri tiles -> full Ztb ----------------
// Each block: one 16-row slab of one lower tile. Sums 16 partials, writes
// Ztb[m][n]; for off-diag tiles also writes the mirrored Ztb[n][m] via LDS
// transpose (Z symmetric). Diag elements -> zdiag (f32), zeroed in Ztb.
__global__ __launch_bounds__(256) void k_reduce2(const u16* __restrict__ part,
                                                 u16* __restrict__ Ztb,
                                                 float* __restrict__ zdiag) {
  __shared__ u16 t16[16][128];
  const int tile = blockIdx.x >> 3;
  const int slab = blockIdx.x & 7;
  int tm = 0, a2 = 0;
  while (a2 + tm + 1 <= tile) { ++tm; a2 += tm; }
  const int tn = tile - a2;

  const int rl = slab * 16 + (threadIdx.x >> 4);   // 0..127 row in tile
  const int cl0 = (threadIdx.x & 15) * 8;          // col start
  const size_t eo = (size_t)tile * 16384 + (size_t)rl * 128 + cl0;

  float s[8] = {0, 0, 0, 0, 0, 0, 0, 0};
#pragma unroll
  for (int p = 0; p < 16; ++p) {
    ushort8 pk = *(const ushort8*)(part + (size_t)p * (36 * 16384) + eo);
#pragma unroll
    for (int j = 0; j < 8; ++j) s[j] += bf2f(pk[j]);
  }
  const int m = tm * 128 + rl;
  ushort8 o;
#pragma unroll
  for (int j = 0; j < 8; ++j) {
    const int n = tn * 128 + cl0 + j;
    if (m == n) { zdiag[m] = s[j]; o[j] = 0; }
    else o[j] = f2bf(s[j]);
  }
  *(ushort8*)(Ztb + (size_t)m * 1024 + tn * 128 + cl0) = o;

  if (tm != tn) {
    *(ushort8*)(&t16[threadIdx.x >> 4][cl0]) = o;
    __syncthreads();
    // mirror: Ztb[tn*128 + c][tm*128 + slab*16 + k] = t16[k][c]
    const int c = threadIdx.x >> 1;
    const int kh = (threadIdx.x & 1) * 8;
    ushort8 g;
#pragma unroll
    for (int j = 0; j < 8; ++j) g[j] = t16[kh + j][c];
    *(ushort8*)(Ztb + (size_t)(tn * 128 + c) * 1024 + tm * 128 + slab * 16 + kh) = g;
  }
}

extern "C" void kernel_launch(void* const* d_in, const int* in_sizes, int n_in,
                              void* d_out, int out_size, void* d_ws, size_t ws_size,
                              hipStream_t stream) {
  const float* x = (const float*)d_in[0];
  float* out = (float*)d_out;
  char* ws = (char*)d_ws;

  // ws layout (~50.1 MB): rnorm | Y | Yt | Xt | Ztb | zdiag
  float* rnorm = (float*)ws;                                   // 32 KB
  u16* Y    = (u16*)(ws + (1u << 16));                         // 16 MB
  u16* Yt   = (u16*)(ws + (1u << 16) + (16u << 20));           // 16 MB
  u16* Xt   = (u16*)(ws + (1u << 16) + (32u << 20));           // 16 MB
  u16* Ztb  = (u16*)(ws + (1u << 16) + (48u << 20));           // 2 MB
  float* zdiag = (float*)(ws + (1u << 16) + (50u << 20));      // 4 KB
  u16* part = (u16*)d_out;  // 16 x 36-tile bf16 partials (18.4 MB of 32 MB)

  k_rownorm<<<8192, 256, 0, stream>>>(x, rnorm);
  k_build<<<dim3(16, 128), 256, 0, stream>>>(x, rnorm, Y, Yt, Xt);
  // Z lower-tri tiles: 36 tiles x 16 k-slices
  k_gemm_bt<0><<<576, 256, 0, stream>>>(Xt, Yt, part, nullptr, nullptr, nullptr);
  k_reduce2<<<288, 256, 0, stream>>>(part, Ztb, zdiag);
  // out[i][d] = sigmoid( sum_k Y[i][k]*Ztb[d][k] + x[i][d]*rn[i]*zdiag[d] )
  k_gemm_bt<1><<<512, 256, 0, stream>>>(Y, Ztb, out, x, rnorm, zdiag);
}

// Round 6
// 76.992 us; speedup vs baseline: 1.2754x; 1.0362x over previous
//
#include <hip/hip_runtime.h>
#include <cstdint>

typedef __bf16 v8bf __attribute__((ext_vector_type(8)));
typedef float f32x4 __attribute__((ext_vector_type(4)));
typedef int i32x4 __attribute__((ext_vector_type(4)));
typedef uint16_t u16;
typedef uint32_t u32;
typedef u16 ushort8 __attribute__((ext_vector_type(8)));

__device__ __forceinline__ u16 f2bf(float f) {
  u32 u = __float_as_uint(f);
  u += 0x7FFFu + ((u >> 16) & 1u);   // round-to-nearest-even
  return (u16)(u >> 16);
}
__device__ __forceinline__ float bf2f(u16 h) {
  return __uint_as_float((u32)h << 16);
}

#define AS1(p) ((__attribute__((address_space(1))) void*)(p))

__device__ __forceinline__ v8bf ds_read_b128f(u32 addr) {
  i32x4 r;
  asm volatile("ds_read_b128 %0, %1" : "=v"(r) : "v"(addr));
  return __builtin_bit_cast(v8bf, r);
}

// Counted waits: NO clobbers (a "memory" clobber makes the waitcnt pass treat
// the asm as a memory op and pre-drain). Order pinned with sched_barrier(0).
#define WAITV(N)                                         \
  do {                                                   \
    __builtin_amdgcn_sched_barrier(0);                   \
    asm volatile("s_waitcnt vmcnt(" #N ")");             \
    __builtin_amdgcn_sched_barrier(0);                   \
  } while (0)
#define WAITL(N)                                         \
  do {                                                   \
    __builtin_amdgcn_sched_barrier(0);                   \
    asm volatile("s_waitcnt lgkmcnt(" #N ")");           \
    __builtin_amdgcn_sched_barrier(0);                   \
  } while (0)

// ---------------- K1: 1/||x_row|| ----------------
__global__ __launch_bounds__(256) void k_rownorm(const float* __restrict__ x,
                                                 float* __restrict__ rnorm) {
  const int row = blockIdx.x;
  const float4 v = ((const float4*)(x + (size_t)row * 1024))[threadIdx.x];
  float s = v.x * v.x + v.y * v.y + v.z * v.z + v.w * v.w;
#pragma unroll
  for (int off = 32; off > 0; off >>= 1) s += __shfl_down(s, off, 64);
  __shared__ float ps[4];
  if ((threadIdx.x & 63) == 0) ps[threadIdx.x >> 6] = s;
  __syncthreads();
  if (threadIdx.x == 0) {
    float t = ps[0] + ps[1] + ps[2] + ps[3];
    rnorm[row] = 1.0f / sqrtf(t);  // norms ~32, eps clamp never binds
  }
}

// ---------------- K2: build Y = bf16(x*rn) [8192][1024], Wt = bf16(x*sqrt(rn))^T [1024][8192] ----------------
// Z = W^T W (SYRK form): Z[d][e] = sum_i x_id*x_ie*rn_i  — single staged operand.
__global__ __launch_bounds__(256) void k_build(const float* __restrict__ x,
                                               const float* __restrict__ rnorm,
                                               u16* __restrict__ Y,
                                               u16* __restrict__ Wt) {
  __shared__ float tile[64][65];
  __shared__ float rn[64], sq[64];
  const int d0 = blockIdx.x * 64;   // 0..1023
  const int i0 = blockIdx.y * 64;   // 0..8191
  const int tr = threadIdx.x >> 6;  // 0..3
  const int tc = threadIdx.x & 63;
#pragma unroll
  for (int it = 0; it < 16; ++it) {
    int r = it * 4 + tr;
    tile[r][tc] = x[(size_t)(i0 + r) * 1024 + d0 + tc];
  }
  if (threadIdx.x < 64) {
    float rv = rnorm[i0 + threadIdx.x];
    rn[threadIdx.x] = rv;
    sq[threadIdx.x] = sqrtf(rv);
  }
  __syncthreads();
#pragma unroll
  for (int it = 0; it < 16; ++it) {
    int r = it * 4 + tr;
    Y[(size_t)(i0 + r) * 1024 + d0 + tc] = f2bf(tile[r][tc] * rn[r]);
  }
#pragma unroll
  for (int it = 0; it < 16; ++it) {
    int rr = it * 4 + tr;            // d within tile
    Wt[(size_t)(d0 + rr) * 8192 + i0 + tc] = f2bf(tile[tc][rr] * sq[tc]);
  }
}

// ---------------- GEMM: C = A[M][K] * B[N][K]^T, bf16 in, f32 acc ----------------
// BM=256 x BN=128 tile, BK=64, 8 waves (4x2), each wave 64x64 = 4x4 frags of
// 16x16x32 MFMA. 96KB LDS: A [2][256][64] @0, B [2][128][64] @65536.
// XOR-swizzle (R4-verified conflict-free): 16B slot ^= (row&7); inverse swizzle
// applied on the per-lane global source address (global_load_lds dest linear).
// 2-buffer ring, depth-1 prefetch, counted vmcnt(6) (6 loads/wave/tile).
// Grid = 256 blocks = exactly 1 block/CU (512 thr), zero tail.
// MODE 0: Z = Wt*Wt^T (full), split-K=8, zi=b&7 so each XCD owns one K-slice
//   (2MB Wt band L2-resident). bf16 partial out.
// MODE 1: out = sigmoid(Y*Ztb^T + x*rn*zdiag), 4 m-panels per XCD.
template <int MODE>
__global__ __launch_bounds__(512, 1) void k_gemm256(
    const u16* __restrict__ A, const u16* __restrict__ B, void* __restrict__ Cv,
    const float* __restrict__ Xf, const float* __restrict__ rnorm,
    const float* __restrict__ zdiag) {
  __shared__ char lds[98304] __attribute__((aligned(16)));
  const int tid = threadIdx.x;
  const int wave = tid >> 6;      // 0..7
  const int lane = tid & 63;
  const int wm = wave >> 1;       // 0..3
  const int wn = wave & 1;        // 0..1

  int m0, n0, k_start, K;
  int zi = 0, tile = 0;
  if (MODE == 0) {
    zi = blockIdx.x & 7;          // K-slice -> XCD
    tile = blockIdx.x >> 3;       // 0..31
    m0 = (tile >> 3) * 256;
    n0 = (tile & 7) * 128;
    k_start = zi * 1024; K = 8192;
  } else {
    const int b = blockIdx.x;
    m0 = ((b & 7) * 4 + ((b >> 3) & 3)) * 256;  // 4 m-panels per XCD
    n0 = (b >> 5) * 128;
    k_start = 0; K = 1024;
  }

  f32x4 acc[4][4] = {};

  const int frow = lane & 15;
  const u32 sw0 = (u32)(((lane >> 4) ^ (frow & 7)) << 4);  // swizzled 16B slot

  // staging: A rows wave*32+j*8+(lane>>3) j=0..3; B rows wave*16+j*8+(lane>>3) j=0..1
  const int srA = lane >> 3;
  const int swz8 = ((lane & 7) ^ srA) << 3;   // inverse-swizzled k-chunk (elems)
  const u16* gA_l = A + (size_t)(m0 + wave * 32 + srA) * K + k_start + swz8;
  const u16* gB_l = B + (size_t)(n0 + wave * 16 + srA) * K + k_start + swz8;

  typedef __attribute__((address_space(3))) char* ldsp;
  ldsp l3 = (ldsp)((__attribute__((address_space(3))) void*)&lds[0]);
  const u32 lds0 = (u32)(uintptr_t)l3;

#define STAGE(buf, kt)                                                         \
  do {                                                                         \
    const size_t _ko = (size_t)(kt) * 64;                                      \
    ldsp _ba = l3 + (buf) * 32768 + wave * 4096;                               \
    ldsp _bb = l3 + 65536 + (buf) * 16384 + wave * 2048;                       \
    _Pragma("unroll")                                                          \
    for (int _j = 0; _j < 4; ++_j)                                             \
      __builtin_amdgcn_global_load_lds(AS1(gA_l + _ko + (size_t)_j * 8 * K),   \
                                       (_ba + _j * 1024), 16, 0, 0);           \
    _Pragma("unroll")                                                          \
    for (int _j = 0; _j < 2; ++_j)                                             \
      __builtin_amdgcn_global_load_lds(AS1(gB_l + _ko + (size_t)_j * 8 * K),   \
                                       (_bb + _j * 1024), 16, 0, 0);           \
  } while (0)

  STAGE(0, 0);
  STAGE(1, 1);
  for (int t = 0; t < 16; ++t) {
    const int buf = t & 1;
    if (t < 15) { WAITV(6); } else { WAITV(0); }  // tile t resident; t+1 in flight
    __builtin_amdgcn_s_barrier();
    const u32 aA = lds0 + (u32)buf * 32768 + (u32)((wm * 64 + frow) * 128) + sw0;
    const u32 aB = lds0 + 65536u + (u32)buf * 16384 + (u32)((wn * 64 + frow) * 128) + sw0;
    v8bf a0[4], b0[4], a1[4], b1[4];
#pragma unroll
    for (int i = 0; i < 4; ++i) a0[i] = ds_read_b128f(aA + i * 2048);
#pragma unroll
    for (int i = 0; i < 4; ++i) b0[i] = ds_read_b128f(aB + i * 2048);
#pragma unroll
    for (int i = 0; i < 4; ++i) a1[i] = ds_read_b128f((aA + i * 2048) ^ 0x40);  // k-step 1
#pragma unroll
    for (int i = 0; i < 4; ++i) b1[i] = ds_read_b128f((aB + i * 2048) ^ 0x40);
    WAITL(8);                        // first 8 (k-step 0) landed
    __builtin_amdgcn_s_setprio(1);
#pragma unroll
    for (int mi = 0; mi < 4; ++mi)
#pragma unroll
      for (int ni = 0; ni < 4; ++ni)
        acc[mi][ni] = __builtin_amdgcn_mfma_f32_16x16x32_bf16(a0[mi], b0[ni], acc[mi][ni], 0, 0, 0);
    __builtin_amdgcn_s_setprio(0);
    WAITL(0);
    __builtin_amdgcn_s_barrier();    // all waves done reading buf -> safe to overwrite
    if (t + 2 < 16) STAGE(buf, t + 2);
    __builtin_amdgcn_s_setprio(1);
#pragma unroll
    for (int mi = 0; mi < 4; ++mi)
#pragma unroll
      for (int ni = 0; ni < 4; ++ni)
        acc[mi][ni] = __builtin_amdgcn_mfma_f32_16x16x32_bf16(a1[mi], b1[ni], acc[mi][ni], 0, 0, 0);
    __builtin_amdgcn_s_setprio(0);
  }
#undef STAGE

  // C/D layout (verified): col = lane&15, row = (lane>>4)*4 + reg
  const int crow = (lane >> 4) * 4;
  const int ccol = lane & 15;
#pragma unroll
  for (int mi = 0; mi < 4; ++mi) {
#pragma unroll
    for (int ni = 0; ni < 4; ++ni) {
      const int rl = wm * 64 + mi * 16 + crow;   // 0..255
      const int cl = wn * 64 + ni * 16 + ccol;   // 0..127
#pragma unroll
      for (int r = 0; r < 4; ++r) {
        float v = acc[mi][ni][r];
        if (MODE == 0) {
          const size_t o = (((size_t)(zi * 32 + tile)) << 15) + (size_t)(rl + r) * 128 + cl;
          ((u16*)Cv)[o] = f2bf(v);               // bf16 partial
        } else {
          const int row = m0 + rl + r;
          const int col = n0 + cl;
          const size_t o = (size_t)row * 1024 + col;
          float z = v + Xf[o] * rnorm[row] * zdiag[col];  // exact diag term
          ((float*)Cv)[o] = 1.0f / (1.0f + __expf(-z));
        }
      }
    }
  }
}

// ---------------- K4: reduce 8 bf16 split-K partials -> bf16 Z (diag zeroed -> zdiag f32) ----------------
// partials layout: part[zi][tile=tm*8+tn][256][128]
__global__ __launch_bounds__(256) void k_reduce1(const u16* __restrict__ part,
                                                 u16* __restrict__ Ztb,
                                                 float* __restrict__ zdiag) {
  const int v = blockIdx.x * 256 + threadIdx.x;  // 0..131071
  const int base = v * 8;                        // over 1024*1024, 8 at a time
  const int m = base >> 10, nn = base & 1023;
  const size_t po = (((size_t)((m >> 8) * 8 + (nn >> 7))) << 15) +
                    (size_t)(m & 255) * 128 + (nn & 127);
  float s[8] = {0, 0, 0, 0, 0, 0, 0, 0};
#pragma unroll
  for (int p = 0; p < 8; ++p) {
    ushort8 pk = *(const ushort8*)(part + (((size_t)p) << 20) + po);
#pragma unroll
    for (int j = 0; j < 8; ++j) s[j] += bf2f(pk[j]);
  }
  ushort8 o;
#pragma unroll
  for (int j = 0; j < 8; ++j) {
    if (m == nn + j) { zdiag[m] = s[j]; o[j] = 0; }
    else o[j] = f2bf(s[j]);
  }
  *(ushort8*)(Ztb + (size_t)m * 1024 + nn) = o;
}

extern "C" void kernel_launch(void* const* d_in, const int* in_sizes, int n_in,
                              void* d_out, int out_size, void* d_ws, size_t ws_size,
                              hipStream_t stream) {
  const float* x = (const float*)d_in[0];
  float* out = (float*)d_out;
  char* ws = (char*)d_ws;

  // ws layout (~34.1 MB): rnorm | Y | Wt | Ztb | zdiag
  float* rnorm = (float*)ws;                                   // 32 KB
  u16* Y    = (u16*)(ws + (1u << 16));                         // 16 MB
  u16* Wt   = (u16*)(ws + (1u << 16) + (16u << 20));           // 16 MB
  u16* Ztb  = (u16*)(ws + (1u << 16) + (32u << 20));           // 2 MB
  float* zdiag = (float*)(ws + (1u << 16) + (34u << 20));      // 4 KB
  u16* part = (u16*)d_out;  // 8 x 2 MB bf16 split-K partials, consumed by k_reduce1

  k_rownorm<<<8192, 256, 0, stream>>>(x, rnorm);
  k_build<<<dim3(16, 128), 256, 0, stream>>>(x, rnorm, Y, Wt);
  // Z[d][e] = sum_i Wt[d][i]*Wt[e][i]  (32 tiles of 256x128 x 8 K-slices = 256 blocks)
  k_gemm256<0><<<256, 512, 0, stream>>>(Wt, Wt, part, nullptr, nullptr, nullptr);
  k_reduce1<<<512, 256, 0, stream>>>(part, Ztb, zdiag);
  // out[i][d] = sigmoid( sum_k Y[i][k]*Ztb[d][k] + x[i][d]*rn[i]*zdiag[d] )  (256 blocks)
  k_gemm256<1><<<256, 512, 0, stream>>>(Y, Ztb, out, x, rnorm, zdiag);
}

// Round 7
// 76.469 us; speedup vs baseline: 1.2842x; 1.0068x over previous
//
#include <hip/hip_runtime.h>
#include <cstdint>

typedef __bf16 v8bf __attribute__((ext_vector_type(8)));
typedef float f32x4 __attribute__((ext_vector_type(4)));
typedef int i32x4 __attribute__((ext_vector_type(4)));
typedef uint16_t u16;
typedef uint32_t u32;
typedef u16 ushort8 __attribute__((ext_vector_type(8)));

__device__ __forceinline__ u16 f2bf(float f) {
  u32 u = __float_as_uint(f);
  u += 0x7FFFu + ((u >> 16) & 1u);   // round-to-nearest-even
  return (u16)(u >> 16);
}
__device__ __forceinline__ float bf2f(u16 h) {
  return __uint_as_float((u32)h << 16);
}

#define AS1(p) ((__attribute__((address_space(1))) void*)(p))

__device__ __forceinline__ v8bf ds_read_b128f(u32 addr) {
  i32x4 r;
  asm volatile("ds_read_b128 %0, %1" : "=v"(r) : "v"(addr));
  return __builtin_bit_cast(v8bf, r);
}

// Counted waits: NO clobbers (a "memory" clobber makes the waitcnt pass treat
// the asm as a memory op and pre-drain). Order pinned with sched_barrier(0).
#define WAITV(N)                                         \
  do {                                                   \
    __builtin_amdgcn_sched_barrier(0);                   \
    asm volatile("s_waitcnt vmcnt(" #N ")");             \
    __builtin_amdgcn_sched_barrier(0);                   \
  } while (0)
#define WAITL(N)                                         \
  do {                                                   \
    __builtin_amdgcn_sched_barrier(0);                   \
    asm volatile("s_waitcnt lgkmcnt(" #N ")");           \
    __builtin_amdgcn_sched_barrier(0);                   \
  } while (0)

// ---------------- K1: 1/||x_row|| ----------------
__global__ __launch_bounds__(256) void k_rownorm(const float* __restrict__ x,
                                                 float* __restrict__ rnorm) {
  const int row = blockIdx.x;
  const float4 v = ((const float4*)(x + (size_t)row * 1024))[threadIdx.x];
  float s = v.x * v.x + v.y * v.y + v.z * v.z + v.w * v.w;
#pragma unroll
  for (int off = 32; off > 0; off >>= 1) s += __shfl_down(s, off, 64);
  __shared__ float ps[4];
  if ((threadIdx.x & 63) == 0) ps[threadIdx.x >> 6] = s;
  __syncthreads();
  if (threadIdx.x == 0) {
    float t = ps[0] + ps[1] + ps[2] + ps[3];
    rnorm[row] = 1.0f / sqrtf(t);  // norms ~32, eps clamp never binds
  }
}

// ---------------- K2: build Y = bf16(x*rn) [8192][1024], Wt = bf16(x*sqrt(rn))^T [1024][8192] ----------------
// Z = W^T W (SYRK form): Z[d][e] = sum_i x_id*x_ie*rn_i  — single staged operand.
__global__ __launch_bounds__(256) void k_build(const float* __restrict__ x,
                                               const float* __restrict__ rnorm,
                                               u16* __restrict__ Y,
                                               u16* __restrict__ Wt) {
  __shared__ float tile[64][65];
  __shared__ float rn[64], sq[64];
  const int d0 = blockIdx.x * 64;   // 0..1023
  const int i0 = blockIdx.y * 64;   // 0..8191
  const int tr = threadIdx.x >> 6;  // 0..3
  const int tc = threadIdx.x & 63;
#pragma unroll
  for (int it = 0; it < 16; ++it) {
    int r = it * 4 + tr;
    tile[r][tc] = x[(size_t)(i0 + r) * 1024 + d0 + tc];
  }
  if (threadIdx.x < 64) {
    float rv = rnorm[i0 + threadIdx.x];
    rn[threadIdx.x] = rv;
    sq[threadIdx.x] = sqrtf(rv);
  }
  __syncthreads();
#pragma unroll
  for (int it = 0; it < 16; ++it) {
    int r = it * 4 + tr;
    Y[(size_t)(i0 + r) * 1024 + d0 + tc] = f2bf(tile[r][tc] * rn[r]);
  }
#pragma unroll
  for (int it = 0; it < 16; ++it) {
    int rr = it * 4 + tr;            // d within tile
    Wt[(size_t)(d0 + rr) * 8192 + i0 + tc] = f2bf(tile[tc][rr] * sq[tc]);
  }
}

// ---------------- GEMM: C = A[M][K] * B[N][K]^T, bf16 in, f32 acc ----------------
// BM=256 x BN=128, BK=64, 8 waves (4x2), wave = 64x64 out = 4x4 frags, 32 MFMA/tile.
// LDS ring-3 (144KB): per buffer A [256][128B] @0, B [128][128B] @32768.
// XOR-swizzle (R4-verified conflict-free). ONE barrier per K-tile; STAGE(t+2)
// issued right AFTER the barrier (WAR-safe: that buffer's reads were lgkm-
// drained before every wave reached this barrier) -> loads ~1.5 tiles in
// flight across barriers; counted vmcnt(6)/lgkmcnt(8) gates.
// MODE 0: Z = Wt*Wt^T, split-K=8, zi=b&7 -> one K-slice per XCD (L2-resident).
// MODE 1: out = sigmoid(Y*Ztb^T + x*rn*zdiag), 4 m-panels per XCD.
template <int MODE>
__global__ __launch_bounds__(512, 1) void k_gemm256(
    const u16* __restrict__ A, const u16* __restrict__ B, void* __restrict__ Cv,
    const float* __restrict__ Xf, const float* __restrict__ rnorm,
    const float* __restrict__ zdiag) {
  __shared__ char lds[3 * 49152] __attribute__((aligned(16)));
  const int tid = threadIdx.x;
  const int wave = tid >> 6;      // 0..7
  const int lane = tid & 63;
  const int wm = wave >> 1;       // 0..3
  const int wn = wave & 1;        // 0..1

  int m0, n0, k_start, K;
  int zi = 0, tile = 0;
  if (MODE == 0) {
    zi = blockIdx.x & 7;          // K-slice -> XCD
    tile = blockIdx.x >> 3;       // 0..31
    m0 = (tile >> 3) * 256;
    n0 = (tile & 7) * 128;
    k_start = zi * 1024; K = 8192;
  } else {
    const int b = blockIdx.x;
    m0 = ((b & 7) * 4 + ((b >> 3) & 3)) * 256;  // 4 m-panels per XCD
    n0 = (b >> 5) * 128;
    k_start = 0; K = 1024;
  }

  f32x4 acc[4][4] = {};

  const int frow = lane & 15;
  const u32 sw0 = (u32)(((lane >> 4) ^ (frow & 7)) << 4);  // swizzled 16B slot

  // staging: A rows wave*32+j*8+(lane>>3) j=0..3; B rows wave*16+j*8+(lane>>3) j=0..1
  const int srA = lane >> 3;
  const int swz8 = ((lane & 7) ^ srA) << 3;   // inverse-swizzled k-chunk (elems)
  const u16* gA_l = A + (size_t)(m0 + wave * 32 + srA) * K + k_start + swz8;
  const u16* gB_l = B + (size_t)(n0 + wave * 16 + srA) * K + k_start + swz8;

  typedef __attribute__((address_space(3))) char* ldsp;
  ldsp l3 = (ldsp)((__attribute__((address_space(3))) void*)&lds[0]);
  const u32 lds0 = (u32)(uintptr_t)l3;

#define STAGE(buf, kt)                                                         \
  do {                                                                         \
    const size_t _ko = (size_t)(kt) * 64;                                      \
    ldsp _ba = l3 + (size_t)(buf) * 49152 + wave * 4096;                       \
    ldsp _bb = l3 + (size_t)(buf) * 49152 + 32768 + wave * 2048;               \
    _Pragma("unroll")                                                          \
    for (int _j = 0; _j < 4; ++_j)                                             \
      __builtin_amdgcn_global_load_lds(AS1(gA_l + _ko + (size_t)_j * 8 * K),   \
                                       (_ba + _j * 1024), 16, 0, 0);           \
    _Pragma("unroll")                                                          \
    for (int _j = 0; _j < 2; ++_j)                                             \
      __builtin_amdgcn_global_load_lds(AS1(gB_l + _ko + (size_t)_j * 8 * K),   \
                                       (_bb + _j * 1024), 16, 0, 0);           \
  } while (0)

  STAGE(0, 0);
  STAGE(1, 1);
  int cbuf = 0;   // buffer holding tile t
  int nbuf = 2;   // buffer to stage tile t+2 into
  for (int t = 0; t < 16; ++t) {
    if (t < 15) { WAITV(6); } else { WAITV(0); }  // tile t resident; t+1 in flight
    __builtin_amdgcn_s_barrier();
    if (t + 2 < 16) STAGE(nbuf, t + 2);           // early issue, ~1.5 tiles ahead
    const u32 bb = lds0 + (u32)cbuf * 49152;
    const u32 aA = bb + (u32)((wm * 64 + frow) * 128) + sw0;
    const u32 aB = bb + 32768u + (u32)((wn * 64 + frow) * 128) + sw0;
    v8bf a0[4], b0[4], a1[4], b1[4];
#pragma unroll
    for (int i = 0; i < 4; ++i) a0[i] = ds_read_b128f(aA + i * 2048);
#pragma unroll
    for (int i = 0; i < 4; ++i) b0[i] = ds_read_b128f(aB + i * 2048);
#pragma unroll
    for (int i = 0; i < 4; ++i) a1[i] = ds_read_b128f((aA + i * 2048) ^ 0x40);  // k-step 1
#pragma unroll
    for (int i = 0; i < 4; ++i) b1[i] = ds_read_b128f((aB + i * 2048) ^ 0x40);
    WAITL(8);                        // k-step 0 frags landed; 9..16 overlap MFMA below
    __builtin_amdgcn_s_setprio(1);
#pragma unroll
    for (int mi = 0; mi < 4; ++mi)
#pragma unroll
      for (int ni = 0; ni < 4; ++ni)
        acc[mi][ni] = __builtin_amdgcn_mfma_f32_16x16x32_bf16(a0[mi], b0[ni], acc[mi][ni], 0, 0, 0);
    __builtin_amdgcn_s_setprio(0);
    WAITL(0);
    __builtin_amdgcn_s_setprio(1);
#pragma unroll
    for (int mi = 0; mi < 4; ++mi)
#pragma unroll
      for (int ni = 0; ni < 4; ++ni)
        acc[mi][ni] = __builtin_amdgcn_mfma_f32_16x16x32_bf16(a1[mi], b1[ni], acc[mi][ni], 0, 0, 0);
    __builtin_amdgcn_s_setprio(0);
    cbuf = (cbuf + 1 == 3) ? 0 : cbuf + 1;
    nbuf = (nbuf + 1 == 3) ? 0 : nbuf + 1;
  }
#undef STAGE

  // C/D layout (verified): col = lane&15, row = (lane>>4)*4 + reg
  const int crow = (lane >> 4) * 4;
  const int ccol = lane & 15;
#pragma unroll
  for (int mi = 0; mi < 4; ++mi) {
#pragma unroll
    for (int ni = 0; ni < 4; ++ni) {
      const int rl = wm * 64 + mi * 16 + crow;   // 0..255
      const int cl = wn * 64 + ni * 16 + ccol;   // 0..127
#pragma unroll
      for (int r = 0; r < 4; ++r) {
        float v = acc[mi][ni][r];
        if (MODE == 0) {
          const size_t o = (((size_t)(zi * 32 + tile)) << 15) + (size_t)(rl + r) * 128 + cl;
          ((u16*)Cv)[o] = f2bf(v);               // bf16 partial
        } else {
          const int row = m0 + rl + r;
          const int col = n0 + cl;
          const size_t o = (size_t)row * 1024 + col;
          float z = v + Xf[o] * rnorm[row] * zdiag[col];  // exact diag term
          ((float*)Cv)[o] = 1.0f / (1.0f + __expf(-z));
        }
      }
    }
  }
}

// ---------------- K4: reduce 8 bf16 split-K partials -> bf16 Z (diag zeroed -> zdiag f32) ----------------
// partials layout: part[zi][tile=tm*8+tn][256][128]
__global__ __launch_bounds__(256) void k_reduce1(const u16* __restrict__ part,
                                                 u16* __restrict__ Ztb,
                                                 float* __restrict__ zdiag) {
  const int v = blockIdx.x * 256 + threadIdx.x;  // 0..131071
  const int base = v * 8;                        // over 1024*1024, 8 at a time
  const int m = base >> 10, nn = base & 1023;
  const size_t po = (((size_t)((m >> 8) * 8 + (nn >> 7))) << 15) +
                    (size_t)(m & 255) * 128 + (nn & 127);
  float s[8] = {0, 0, 0, 0, 0, 0, 0, 0};
#pragma unroll
  for (int p = 0; p < 8; ++p) {
    ushort8 pk = *(const ushort8*)(part + (((size_t)p) << 20) + po);
#pragma unroll
    for (int j = 0; j < 8; ++j) s[j] += bf2f(pk[j]);
  }
  ushort8 o;
#pragma unroll
  for (int j = 0; j < 8; ++j) {
    if (m == nn + j) { zdiag[m] = s[j]; o[j] = 0; }
    else o[j] = f2bf(s[j]);
  }
  *(ushort8*)(Ztb + (size_t)m * 1024 + nn) = o;
}

extern "C" void kernel_launch(void* const* d_in, const int* in_sizes, int n_in,
                              void* d_out, int out_size, void* d_ws, size_t ws_size,
                              hipStream_t stream) {
  const float* x = (const float*)d_in[0];
  float* out = (float*)d_out;
  char* ws = (char*)d_ws;

  // ws layout (~34.1 MB): rnorm | Y | Wt | Ztb | zdiag
  float* rnorm = (float*)ws;                                   // 32 KB
  u16* Y    = (u16*)(ws + (1u << 16));                         // 16 MB
  u16* Wt   = (u16*)(ws + (1u << 16) + (16u << 20));           // 16 MB
  u16* Ztb  = (u16*)(ws + (1u << 16) + (32u << 20));           // 2 MB
  float* zdiag = (float*)(ws + (1u << 16) + (34u << 20));      // 4 KB
  u16* part = (u16*)d_out;  // 8 x 2 MB bf16 split-K partials, consumed by k_reduce1

  k_rownorm<<<8192, 256, 0, stream>>>(x, rnorm);
  k_build<<<dim3(16, 128), 256, 0, stream>>>(x, rnorm, Y, Wt);
  // Z[d][e] = sum_i Wt[d][i]*Wt[e][i]  (32 tiles of 256x128 x 8 K-slices = 256 blocks)
  k_gemm256<0><<<256, 512, 0, stream>>>(Wt, Wt, part, nullptr, nullptr, nullptr);
  k_reduce1<<<512, 256, 0, stream>>>(part, Ztb, zdiag);
  // out[i][d] = sigmoid( sum_k Y[i][k]*Ztb[d][k] + x[i][d]*rn[i]*zdiag[d] )  (256 blocks)
  k_gemm256<1><<<256, 512, 0, stream>>>(Y, Ztb, out, x, rnorm, zdiag);
}

// Round 8
// 75.718 us; speedup vs baseline: 1.2969x; 1.0099x over previous
//
#include <hip/hip_runtime.h>
#include <cstdint>

typedef __bf16 v8bf __attribute__((ext_vector_type(8)));
typedef float f32x4 __attribute__((ext_vector_type(4)));
typedef int i32x4 __attribute__((ext_vector_type(4)));
typedef uint16_t u16;
typedef uint32_t u32;
typedef u16 ushort8 __attribute__((ext_vector_type(8)));

__device__ __forceinline__ u16 f2bf(float f) {
  u32 u = __float_as_uint(f);
  u += 0x7FFFu + ((u >> 16) & 1u);   // round-to-nearest-even
  return (u16)(u >> 16);
}
__device__ __forceinline__ float bf2f(u16 h) {
  return __uint_as_float((u32)h << 16);
}

#define AS1(p) ((__attribute__((address_space(1))) void*)(p))

__device__ __forceinline__ v8bf ds_read_b128f(u32 addr) {
  i32x4 r;
  asm volatile("ds_read_b128 %0, %1" : "=v"(r) : "v"(addr));
  return __builtin_bit_cast(v8bf, r);
}

// Counted waits: NO clobbers; order pinned with sched_barrier(0) (rule #18).
#define WAITV(N)                                         \
  do {                                                   \
    __builtin_amdgcn_sched_barrier(0);                   \
    asm volatile("s_waitcnt vmcnt(" #N ")");             \
    __builtin_amdgcn_sched_barrier(0);                   \
  } while (0)
#define WAITL(N)                                         \
  do {                                                   \
    __builtin_amdgcn_sched_barrier(0);                   \
    asm volatile("s_waitcnt lgkmcnt(" #N ")");           \
    __builtin_amdgcn_sched_barrier(0);                   \
  } while (0)

// ---------------- K1: 1/||x_row|| ----------------
__global__ __launch_bounds__(256) void k_rownorm(const float* __restrict__ x,
                                                 float* __restrict__ rnorm) {
  const int row = blockIdx.x;
  const float4 v = ((const float4*)(x + (size_t)row * 1024))[threadIdx.x];
  float s = v.x * v.x + v.y * v.y + v.z * v.z + v.w * v.w;
#pragma unroll
  for (int off = 32; off > 0; off >>= 1) s += __shfl_down(s, off, 64);
  __shared__ float ps[4];
  if ((threadIdx.x & 63) == 0) ps[threadIdx.x >> 6] = s;
  __syncthreads();
  if (threadIdx.x == 0) {
    float t = ps[0] + ps[1] + ps[2] + ps[3];
    rnorm[row] = 1.0f / sqrtf(t);  // norms ~32, eps clamp never binds
  }
}

// ---------------- K2: build Y = bf16(x*rn) [8192][1024], Wt = bf16(x*sqrt(rn))^T [1024][8192] ----------------
__global__ __launch_bounds__(256) void k_build(const float* __restrict__ x,
                                               const float* __restrict__ rnorm,
                                               u16* __restrict__ Y,
                                               u16* __restrict__ Wt) {
  __shared__ float tile[64][65];
  __shared__ float rn[64], sq[64];
  const int d0 = blockIdx.x * 64;   // 0..1023
  const int i0 = blockIdx.y * 64;   // 0..8191
  const int tr = threadIdx.x >> 6;  // 0..3
  const int tc = threadIdx.x & 63;
#pragma unroll
  for (int it = 0; it < 16; ++it) {
    int r = it * 4 + tr;
    tile[r][tc] = x[(size_t)(i0 + r) * 1024 + d0 + tc];
  }
  if (threadIdx.x < 64) {
    float rv = rnorm[i0 + threadIdx.x];
    rn[threadIdx.x] = rv;
    sq[threadIdx.x] = sqrtf(rv);
  }
  __syncthreads();
#pragma unroll
  for (int it = 0; it < 16; ++it) {
    int r = it * 4 + tr;
    Y[(size_t)(i0 + r) * 1024 + d0 + tc] = f2bf(tile[r][tc] * rn[r]);
  }
#pragma unroll
  for (int it = 0; it < 16; ++it) {
    int rr = it * 4 + tr;            // d within tile
    Wt[(size_t)(d0 + rr) * 8192 + i0 + tc] = f2bf(tile[tc][rr] * sq[tc]);
  }
}

// ---------------- GEMM: C = A[M][K] * B[N][K]^T, bf16 in, f32 acc ----------------
// BM=256 x BN=128, BK=64, 8 waves (4x2), wave 64x64 = 4x4 frags, 32 MFMA/tile.
// LDS ring-3 (144KB). XOR-swizzle (verified conflict-free). One barrier+vmcnt(6)
// per tile. Tile body = 8 fine sub-phases: {2 ds_read(next mi) || 1 gload ||
// counted WAITL || setprio || 4 MFMA} — LDS reads, DMA issues and MFMAs
// interleave instead of alternating (m196/m248: the coarse split is the loser).
// lgkm counts valid: pure-DS stream (DMA counts in vmcnt only), in-order.
// MODE 0: Z = Wt*Wt^T, split-K=8 (zi per XCD, L2-resident band), bf16 partials.
// MODE 1: out = sigmoid(Y*Ztb^T + x*rn*zdiag), 4 m-panels per XCD.
template <int MODE>
__global__ __launch_bounds__(512, 1) void k_gemm256(
    const u16* __restrict__ A, const u16* __restrict__ B, void* __restrict__ Cv,
    const float* __restrict__ Xf, const float* __restrict__ rnorm,
    const float* __restrict__ zdiag) {
  __shared__ char lds[3 * 49152] __attribute__((aligned(16)));
  const int tid = threadIdx.x;
  const int wave = tid >> 6;      // 0..7
  const int lane = tid & 63;
  const int wm = wave >> 1;       // 0..3
  const int wn = wave & 1;        // 0..1

  int m0, n0, k_start, K;
  int zi = 0, tile = 0;
  if (MODE == 0) {
    zi = blockIdx.x & 7;          // K-slice -> XCD
    tile = blockIdx.x >> 3;       // 0..31
    m0 = (tile >> 3) * 256;       // M=1024: 4 m-tiles
    n0 = (tile & 7) * 128;        // N=1024: 8 n-tiles
    k_start = zi * 1024; K = 8192;
  } else {
    const int b = blockIdx.x;
    m0 = ((b & 7) * 4 + ((b >> 3) & 3)) * 256;  // 4 m-panels per XCD
    n0 = (b >> 5) * 128;
    k_start = 0; K = 1024;
  }

  f32x4 acc[4][4] = {};

  const int frow = lane & 15;
  const u32 sw0 = (u32)(((lane >> 4) ^ (frow & 7)) << 4);  // swizzled 16B slot

  // staging: A rows wave*32+j*8+(lane>>3) j=0..3; B rows wave*16+j*8+(lane>>3) j=0..1
  const int srA = lane >> 3;
  const int swz8 = ((lane & 7) ^ srA) << 3;   // inverse-swizzled k-chunk (elems)
  const u16* gA_l = A + (size_t)(m0 + wave * 32 + srA) * K + k_start + swz8;
  const u16* gB_l = B + (size_t)(n0 + wave * 16 + srA) * K + k_start + swz8;

  typedef __attribute__((address_space(3))) char* ldsp;
  ldsp l3 = (ldsp)((__attribute__((address_space(3))) void*)&lds[0]);
  const u32 lds0 = (u32)(uintptr_t)l3;

#define GLOAD_A(buf, kt, j)                                                    \
  __builtin_amdgcn_global_load_lds(                                            \
      AS1(gA_l + (size_t)(kt) * 64 + (size_t)(j) * 8 * K),                     \
      (l3 + (size_t)(buf) * 49152 + wave * 4096 + (j) * 1024), 16, 0, 0)
#define GLOAD_B(buf, kt, j)                                                    \
  __builtin_amdgcn_global_load_lds(                                            \
      AS1(gB_l + (size_t)(kt) * 64 + (size_t)(j) * 8 * K),                     \
      (l3 + (size_t)(buf) * 49152 + 32768 + wave * 2048 + (j) * 1024), 16, 0, 0)
#define STAGE6(buf, kt)                                                        \
  do {                                                                         \
    GLOAD_A(buf, kt, 0); GLOAD_A(buf, kt, 1);                                  \
    GLOAD_A(buf, kt, 2); GLOAD_A(buf, kt, 3);                                  \
    GLOAD_B(buf, kt, 0); GLOAD_B(buf, kt, 1);                                  \
  } while (0)

#define MFMA4(ar, barr)                                                        \
  do {                                                                         \
    __builtin_amdgcn_s_setprio(1);                                             \
    acc[_mi][0] = __builtin_amdgcn_mfma_f32_16x16x32_bf16((ar), (barr)[0], acc[_mi][0], 0, 0, 0); \
    acc[_mi][1] = __builtin_amdgcn_mfma_f32_16x16x32_bf16((ar), (barr)[1], acc[_mi][1], 0, 0, 0); \
    acc[_mi][2] = __builtin_amdgcn_mfma_f32_16x16x32_bf16((ar), (barr)[2], acc[_mi][2], 0, 0, 0); \
    acc[_mi][3] = __builtin_amdgcn_mfma_f32_16x16x32_bf16((ar), (barr)[3], acc[_mi][3], 0, 0, 0); \
    __builtin_amdgcn_s_setprio(0);                                             \
  } while (0)

  STAGE6(0, 0);
  STAGE6(1, 1);
  int cbuf = 0;   // buffer holding tile t
  int nbuf = 2;   // buffer receiving tile t+2
  for (int t = 0; t < 16; ++t) {
    if (t < 15) { WAITV(6); } else { WAITV(0); }
    __builtin_amdgcn_s_barrier();         // all waves' tile-t DMA landed
    const u32 bb = lds0 + (u32)cbuf * 49152;
    const u32 aA = bb + (u32)((wm * 64 + frow) * 128) + sw0;
    const u32 aB = bb + 32768u + (u32)((wn * 64 + frow) * 128) + sw0;
    const bool pf = (t + 2 < 16);
    v8bf a0[4], a1[4], b0[4], b1[4];
    // issue order (counted lgkm relies on it): b0*4, a0[0], b1*4, a1[0]
    b0[0] = ds_read_b128f(aB);
    b0[1] = ds_read_b128f(aB + 2048);
    b0[2] = ds_read_b128f(aB + 4096);
    b0[3] = ds_read_b128f(aB + 6144);
    a0[0] = ds_read_b128f(aA);
    b1[0] = ds_read_b128f(aB ^ 0x40);
    b1[1] = ds_read_b128f((aB + 2048) ^ 0x40);
    b1[2] = ds_read_b128f((aB + 4096) ^ 0x40);
    b1[3] = ds_read_b128f((aB + 6144) ^ 0x40);
    a1[0] = ds_read_b128f(aA ^ 0x40);
    if (pf) GLOAD_A(nbuf, t + 2, 0);
    WAITL(5);                                   // b0*,a0[0] ready
    { const int _mi = 0; MFMA4(a0[0], b0); }
    a0[1] = ds_read_b128f(aA + 2048);
    a1[1] = ds_read_b128f((aA + 2048) ^ 0x40);
    if (pf) GLOAD_A(nbuf, t + 2, 1);
    WAITL(2);                                   // b1*,a1[0] ready
    { const int _mi = 0; MFMA4(a1[0], b1); }
    a0[2] = ds_read_b128f(aA + 4096);
    a1[2] = ds_read_b128f((aA + 4096) ^ 0x40);
    if (pf) GLOAD_A(nbuf, t + 2, 2);
    WAITL(3);                                   // a0[1] ready
    { const int _mi = 1; MFMA4(a0[1], b0); }
    a0[3] = ds_read_b128f(aA + 6144);
    a1[3] = ds_read_b128f((aA + 6144) ^ 0x40);
    if (pf) GLOAD_A(nbuf, t + 2, 3);
    WAITL(4);                                   // a1[1] ready
    { const int _mi = 1; MFMA4(a1[1], b1); }
    if (pf) GLOAD_B(nbuf, t + 2, 0);
    WAITL(3);                                   // a0[2] ready
    { const int _mi = 2; MFMA4(a0[2], b0); }
    if (pf) GLOAD_B(nbuf, t + 2, 1);
    WAITL(2);                                   // a1[2] ready
    { const int _mi = 2; MFMA4(a1[2], b1); }
    WAITL(1);                                   // a0[3] ready
    { const int _mi = 3; MFMA4(a0[3], b0); }
    WAITL(0);                                   // a1[3] ready
    { const int _mi = 3; MFMA4(a1[3], b1); }
    cbuf = (cbuf + 1 == 3) ? 0 : cbuf + 1;
    nbuf = (nbuf + 1 == 3) ? 0 : nbuf + 1;
  }
#undef STAGE6
#undef GLOAD_A
#undef GLOAD_B
#undef MFMA4

  // C/D layout (verified): col = lane&15, row = (lane>>4)*4 + reg
  const int crow = (lane >> 4) * 4;
  const int ccol = lane & 15;
#pragma unroll
  for (int mi = 0; mi < 4; ++mi) {
#pragma unroll
    for (int ni = 0; ni < 4; ++ni) {
      const int rl = wm * 64 + mi * 16 + crow;   // 0..255
      const int cl = wn * 64 + ni * 16 + ccol;   // 0..127
#pragma unroll
      for (int r = 0; r < 4; ++r) {
        float v = acc[mi][ni][r];
        if (MODE == 0) {
          const size_t o = (((size_t)(zi * 32 + tile)) << 15) + (size_t)(rl + r) * 128 + cl;
          ((u16*)Cv)[o] = f2bf(v);               // bf16 partial
        } else {
          const int row = m0 + rl + r;
          const int col = n0 + cl;
          const size_t o = (size_t)row * 1024 + col;
          float z = v + Xf[o] * rnorm[row] * zdiag[col];  // exact diag term
          ((float*)Cv)[o] = 1.0f / (1.0f + __expf(-z));
        }
      }
    }
  }
}

// ---------------- K4: reduce 8 bf16 split-K partials -> bf16 Z (diag -> zdiag f32) ----------------
// partials layout: part[zi][tile=(m>>8)*8+(n>>7)][256][128]
__global__ __launch_bounds__(256) void k_reduce1(const u16* __restrict__ part,
                                                 u16* __restrict__ Ztb,
                                                 float* __restrict__ zdiag) {
  const int v = blockIdx.x * 256 + threadIdx.x;  // 0..131071
  const int base = v * 8;                        // over 1024*1024, 8 at a time
  const int m = base >> 10, nn = base & 1023;
  const size_t po = (((size_t)((m >> 8) * 8 + (nn >> 7))) << 15) +
                    (size_t)(m & 255) * 128 + (nn & 127);
  float s[8] = {0, 0, 0, 0, 0, 0, 0, 0};
#pragma unroll
  for (int p = 0; p < 8; ++p) {
    ushort8 pk = *(const ushort8*)(part + (((size_t)p) << 20) + po);
#pragma unroll
    for (int j = 0; j < 8; ++j) s[j] += bf2f(pk[j]);
  }
  ushort8 o;
#pragma unroll
  for (int j = 0; j < 8; ++j) {
    if (m == nn + j) { zdiag[m] = s[j]; o[j] = 0; }
    else o[j] = f2bf(s[j]);
  }
  *(ushort8*)(Ztb + (size_t)m * 1024 + nn) = o;
}

extern "C" void kernel_launch(void* const* d_in, const int* in_sizes, int n_in,
                              void* d_out, int out_size, void* d_ws, size_t ws_size,
                              hipStream_t stream) {
  const float* x = (const float*)d_in[0];
  float* out = (float*)d_out;
  char* ws = (char*)d_ws;

  // ws layout (~34.1 MB): rnorm | Y | Wt | Ztb | zdiag
  float* rnorm = (float*)ws;                                   // 32 KB
  u16* Y    = (u16*)(ws + (1u << 16));                         // 16 MB
  u16* Wt   = (u16*)(ws + (1u << 16) + (16u << 20));           // 16 MB
  u16* Ztb  = (u16*)(ws + (1u << 16) + (32u << 20));           // 2 MB
  float* zdiag = (float*)(ws + (1u << 16) + (34u << 20));      // 4 KB
  u16* part = (u16*)d_out;  // 8 x 4 MB bf16 split-K partials (32 MB = d_out)

  k_rownorm<<<8192, 256, 0, stream>>>(x, rnorm);
  k_build<<<dim3(16, 128), 256, 0, stream>>>(x, rnorm, Y, Wt);
  // Z[d][e] = sum_i Wt[d][i]*Wt[e][i]  (32 tiles of 256x128 x 8 K-slices = 256 blocks)
  k_gemm256<0><<<256, 512, 0, stream>>>(Wt, Wt, part, nullptr, nullptr, nullptr);
  k_reduce1<<<512, 256, 0, stream>>>(part, Ztb, zdiag);
  // out[i][d] = sigmoid( sum_k Y[i][k]*Ztb[d][k] + x[i][d]*rn[i]*zdiag[d] )  (256 blocks)
  k_gemm256<1><<<256, 512, 0, stream>>>(Y, Ztb, out, x, rnorm, zdiag);
}